// Round 3
// baseline (908.599 us; speedup 1.0000x reference)
//
#include <hip/hip_runtime.h>
#include <hip/hip_bf16.h>
#include <math.h>

#define BB 4
#define LL 512
#define D0 640
#define PP 128
#define CC 32
#define NLAYER 3
#define NN (BB*LL)      // 2048
#define RADIN 130

typedef __attribute__((ext_vector_type(8))) short bf16x8;
typedef __attribute__((ext_vector_type(4))) float f32x4;

__device__ __forceinline__ short f2b(float v) {
    __hip_bfloat16 h = __float2bfloat16(v);
    short s; __builtin_memcpy(&s, &h, 2); return s;
}
__device__ __forceinline__ float b2f(short s) {
    unsigned int u = ((unsigned int)(unsigned short)s) << 16;
    float f; __builtin_memcpy(&f, &u, 4); return f;
}
__device__ __forceinline__ void fsplit(float v, short* hi, short* lo) {
    short h = f2b(v);
    *hi = h;
    *lo = f2b(v - b2f(h));
}

// ---------------- setup kernels ----------------

// h0 = seq_rep @ Win0   (one wave per node; lanes 0..31 chan, halves split K)
__global__ __launch_bounds__(64) void k_init_h0(const float* __restrict__ seq,
                                                const float* __restrict__ Win0,
                                                float* __restrict__ h0) {
    const int n = blockIdx.x, lane = threadIdx.x;
    const int c = lane & 31, half = lane >> 5;
    const float* s = seq + (size_t)n * D0;
    float acc = 0.f;
    const int i0 = half * (D0 / 2), i1 = i0 + (D0 / 2);
    for (int i = i0; i < i1; ++i) acc = fmaf(s[i], Win0[i * CC + c], acc);
    acc += __shfl_xor(acc, 32);
    if (lane < 32) h0[n * CC + c] = acc;
}

// h1[n,c,d] = x[n,d] * Win1[c]
__global__ void k_init_h1(const float* __restrict__ x, const float* __restrict__ Win1,
                          float* __restrict__ h1) {
    int idx = blockIdx.x * blockDim.x + threadIdx.x;
    if (idx >= NN * CC) return;
    int n = idx >> 5, c = idx & 31;
    float w = Win1[c];
    const float* xp = x + n * 3;
    float* hp = h1 + (size_t)n * 96 + c * 3;
    hp[0] = xp[0] * w; hp[1] = xp[1] * w; hp[2] = xp[2] * w;
}

// per-edge geometry: r, rhat
__global__ void k_geom(const int* __restrict__ src, const int* __restrict__ dst,
                       const float* __restrict__ x, float* __restrict__ r_e,
                       float* __restrict__ rhat, int E) {
    int e = blockIdx.x * blockDim.x + threadIdx.x;
    if (e >= E) return;
    int s = src[e], d = dst[e];
    float dx = x[d * 3 + 0] - x[s * 3 + 0];
    float dy = x[d * 3 + 1] - x[s * 3 + 1];
    float dz = x[d * 3 + 2] - x[s * 3 + 2];
    float r = sqrtf(dx * dx + dy * dy + dz * dz + 1e-12f);
    float ir = 1.f / (r + 1e-8f);
    r_e[e] = r;
    rhat[e * 3 + 0] = dx * ir; rhat[e * 3 + 1] = dy * ir; rhat[e * 3 + 2] = dz * ir;
}

// rowptr[n] = lower_bound(src, n)  (edges are sorted by (src,dst))
__global__ void k_rowptr(const int* __restrict__ src, int* __restrict__ rowptr, int E) {
    int n = blockIdx.x * blockDim.x + threadIdx.x;
    if (n > NN) return;
    int lo = 0, hi = E;
    while (lo < hi) { int mid = (lo + hi) >> 1; if (src[mid] < n) lo = mid + 1; else hi = mid; }
    rowptr[n] = lo;
}

// rev[e] = index of reversed edge (d,s); graph is symmetric, dst sorted within src block
__global__ void k_rev(const int* __restrict__ src, const int* __restrict__ dst,
                      const int* __restrict__ rowptr, int* __restrict__ rev, int E) {
    int e = blockIdx.x * blockDim.x + threadIdx.x;
    if (e >= E) return;
    int s = src[e], d = dst[e];
    int lo = rowptr[d], hi = rowptr[d + 1];
    while (lo < hi) { int mid = (lo + hi) >> 1; if (dst[mid] < s) lo = mid + 1; else hi = mid; }
    rev[e] = lo;
}

// build split-bf16 ef rows [E][160] (pad 130->160 with zeros); one wave per edge
__global__ __launch_bounds__(256) void k_build_ef(
    const int* __restrict__ src, const int* __restrict__ dst,
    const float* __restrict__ pair, const float* __restrict__ bppm,
    const float* __restrict__ r_e, short* __restrict__ efh, short* __restrict__ efl, int E)
{
    int e = blockIdx.x * 4 + (threadIdx.x >> 6);
    int lane = threadIdx.x & 63;
    if (e >= E) return;
    int s = src[e], d = dst[e];
    int b = s / LL, si = s % LL, di = d % LL;
    size_t prow = ((size_t)b * LL + si) * LL + di;
    const float* pr = pair + prow * PP;
    short* oh = efh + (size_t)e * 160;
    short* ol = efl + (size_t)e * 160;
    short hi, lo;
    fsplit(pr[lane], &hi, &lo); oh[lane] = hi; ol[lane] = lo;
    fsplit(pr[64 + lane], &hi, &lo); oh[64 + lane] = hi; ol[64 + lane] = lo;
    if (lane < 32) {
        int idx = 128 + lane;
        float v = 0.f;
        if (idx == 128) v = bppm[prow];
        else if (idx == 129) v = r_e[e];
        fsplit(v, &hi, &lo); oh[idx] = hi; ol[idx] = lo;
    }
}

// pack Wr1/Wr2 into MFMA B-fragment order, split hi/lo
// W1: [NL][5][4][64][8] ; W2: [NL][2][8][64][8]
__global__ void k_pack(const float* __restrict__ Wr1, const float* __restrict__ Wr2,
                       short* __restrict__ W1h, short* __restrict__ W1l,
                       short* __restrict__ W2h, short* __restrict__ W2l) {
    int t = blockIdx.x * blockDim.x + threadIdx.x;
    const int tot1 = NLAYER * 5 * 4 * 64 * 8;
    const int tot2 = NLAYER * 2 * 8 * 64 * 8;
    short hi, lo;
    if (t < tot1) {
        int j = t & 7; int r = t >> 3;
        int ln = r & 63; r >>= 6;
        int cb = r & 3; r >>= 2;
        int kb = r % 5; int l = r / 5;
        int row = kb * 32 + (ln >> 4) * 8 + j;
        int col = cb * 16 + (ln & 15);
        float v = (row < RADIN) ? Wr1[((size_t)l * RADIN + row) * 64 + col] : 0.f;
        fsplit(v, &hi, &lo); W1h[t] = hi; W1l[t] = lo;
    } else if (t < tot1 + tot2) {
        int t2 = t - tot1;
        int j = t2 & 7; int r = t2 >> 3;
        int ln = r & 63; r >>= 6;
        int cb = r & 7; r >>= 3;
        int kb = r & 1; int l = r >> 1;
        int row = kb * 32 + (ln >> 4) * 8 + j;
        int col = cb * 16 + (ln & 15);
        float v = Wr2[((size_t)l * 64 + row) * 128 + col];
        fsplit(v, &hi, &lo); W2h[t2] = hi; W2l[t2] = lo;
    }
}

// ---------------- initial node precompute (layer 0) ----------------
__global__ __launch_bounds__(256) void k_nodepre(
    int l, const float* __restrict__ h0, const float* __restrict__ h1,
    const float* __restrict__ Wq, const float* __restrict__ Wm00,
    const float* __restrict__ Wm10, const float* __restrict__ Wm11,
    float* __restrict__ qbuf, float* __restrict__ P00,
    float* __restrict__ P10, float* __restrict__ P11)
{
    __shared__ float sh0[8][32], sh1[8][96];
    const int c = threadIdx.x & 31, hw = threadIdx.x >> 5;
    const int n = blockIdx.x * 8 + hw;
    sh0[hw][c] = h0[n * CC + c];
    const float* hp = h1 + (size_t)n * 96 + c * 3;
    sh1[hw][c * 3 + 0] = hp[0]; sh1[hw][c * 3 + 1] = hp[1]; sh1[hw][c * 3 + 2] = hp[2];
    const float* WqL  = Wq   + l * 1024;
    const float* W00L = Wm00 + l * 1024;
    const float* W10L = Wm10 + l * 1024;
    const float* W11L = Wm11 + l * 1024;
    float q = 0.f, p00 = 0.f, p10 = 0.f, px = 0.f, py = 0.f, pz = 0.f;
    for (int i = 0; i < 32; ++i) {
        float a = sh0[hw][i];
        q   = fmaf(a, WqL[i * 32 + c], q);
        p00 = fmaf(a, W00L[i * 32 + c], p00);
        p10 = fmaf(a, W10L[i * 32 + c], p10);
        float w = W11L[i * 32 + c];
        px = fmaf(sh1[hw][i * 3 + 0], w, px);
        py = fmaf(sh1[hw][i * 3 + 1], w, py);
        pz = fmaf(sh1[hw][i * 3 + 2], w, pz);
    }
    qbuf[n * 32 + c] = q; P00[n * 32 + c] = p00; P10[n * 32 + c] = p10;
    float* pp = P11 + (size_t)n * 96 + c * 3;
    pp[0] = px; pp[1] = py; pp[2] = pz;
}

// ---------------- radial MLP, all 3 layers, split-bf16 MFMA ----------------
// block = 256 (4 waves); wave tile = 16 edges; A-fragments loaded once, reused 3 layers
__global__ __launch_bounds__(256) void k_radial3(
    int E,
    const short* __restrict__ efh, const short* __restrict__ efl,
    const short* __restrict__ W1h, const short* __restrict__ W1l,
    const short* __restrict__ W2h, const short* __restrict__ W2l,
    const float* __restrict__ br1, const float* __restrict__ br2,
    float* __restrict__ rad3)
{
    __shared__ short s_hh[4][16][72], s_hl[4][16][72];
    const int lane = threadIdx.x & 63, wv = threadIdx.x >> 6;
    const int r16 = lane & 15, q4 = lane >> 4;
    const int e0 = blockIdx.x * 64 + wv * 16;
    int row = e0 + r16; if (row >= E) row = E - 1;

    bf16x8 ah[5], al[5];
    {
        const short* arh = efh + (size_t)row * 160 + q4 * 8;
        const short* arl = efl + (size_t)row * 160 + q4 * 8;
        for (int kb = 0; kb < 5; ++kb) {
            ah[kb] = *(const bf16x8*)(arh + kb * 32);
            al[kb] = *(const bf16x8*)(arl + kb * 32);
        }
    }

    for (int l = 0; l < NLAYER; ++l) {
        // ---- GEMM1: [16 x 160] @ [160 x 64], 3-pass split ----
        f32x4 acc[4];
        for (int cb = 0; cb < 4; ++cb) { acc[cb][0]=0.f; acc[cb][1]=0.f; acc[cb][2]=0.f; acc[cb][3]=0.f; }
        const short* b1h = W1h + (size_t)l * 10240 + lane * 8;
        const short* b1l = W1l + (size_t)l * 10240 + lane * 8;
        for (int kb = 0; kb < 5; ++kb) {
            for (int cb = 0; cb < 4; ++cb) {
                bf16x8 bh = *(const bf16x8*)(b1h + (kb * 4 + cb) * 512);
                bf16x8 bl = *(const bf16x8*)(b1l + (kb * 4 + cb) * 512);
                acc[cb] = __builtin_amdgcn_mfma_f32_16x16x32_bf16(ah[kb], bh, acc[cb], 0, 0, 0);
                acc[cb] = __builtin_amdgcn_mfma_f32_16x16x32_bf16(al[kb], bh, acc[cb], 0, 0, 0);
                acc[cb] = __builtin_amdgcn_mfma_f32_16x16x32_bf16(ah[kb], bl, acc[cb], 0, 0, 0);
            }
        }
        __syncthreads();   // previous layer's s_h reads complete
        // bias + relu, stash split-bf16  (C/D: col=lane&15, row=(lane>>4)*4+i)
        for (int cb = 0; cb < 4; ++cb) {
            int col = cb * 16 + r16;
            float b = br1[l * 64 + col];
            for (int i = 0; i < 4; ++i) {
                float h = fmaxf(acc[cb][i] + b, 0.f);
                short hh = f2b(h);
                s_hh[wv][q4 * 4 + i][col] = hh;
                s_hl[wv][q4 * 4 + i][col] = f2b(h - b2f(hh));
            }
        }
        __syncthreads();
        // ---- GEMM2: [16 x 64] @ [64 x 128], 3-pass split ----
        f32x4 o[8];
        for (int cb = 0; cb < 8; ++cb) { o[cb][0]=0.f; o[cb][1]=0.f; o[cb][2]=0.f; o[cb][3]=0.f; }
        const short* b2h = W2h + (size_t)l * 8192 + lane * 8;
        const short* b2l = W2l + (size_t)l * 8192 + lane * 8;
        for (int kb = 0; kb < 2; ++kb) {
            bf16x8 a2h = *(const bf16x8*)(&s_hh[wv][r16][kb * 32 + q4 * 8]);
            bf16x8 a2l = *(const bf16x8*)(&s_hl[wv][r16][kb * 32 + q4 * 8]);
            for (int cb = 0; cb < 8; ++cb) {
                bf16x8 bh = *(const bf16x8*)(b2h + (kb * 8 + cb) * 512);
                bf16x8 bl = *(const bf16x8*)(b2l + (kb * 8 + cb) * 512);
                o[cb] = __builtin_amdgcn_mfma_f32_16x16x32_bf16(a2h, bh, o[cb], 0, 0, 0);
                o[cb] = __builtin_amdgcn_mfma_f32_16x16x32_bf16(a2l, bh, o[cb], 0, 0, 0);
                o[cb] = __builtin_amdgcn_mfma_f32_16x16x32_bf16(a2h, bl, o[cb], 0, 0, 0);
            }
        }
        float* radl = rad3 + (size_t)l * E * 128;
        for (int cb = 0; cb < 8; ++cb) {
            int col = cb * 16 + r16;
            float b = br2[l * 128 + col];
            for (int i = 0; i < 4; ++i) {
                int er = e0 + q4 * 4 + i;
                if (er < E) radl[(size_t)er * 128 + col] = o[cb][i] + b;
            }
        }
    }
}

// ---------------- edge epilogue: m0, m1 scattered to rev[e] ----------------
__global__ __launch_bounds__(256) void k_edge2(
    int l, int E, const int* __restrict__ src, const int* __restrict__ rev,
    const float* __restrict__ rhat, const float* __restrict__ rad3,
    const float* __restrict__ h1, const float* __restrict__ Wm01,
    const float* __restrict__ P00, const float* __restrict__ P10,
    const float* __restrict__ P11,
    float* __restrict__ m0buf, float* __restrict__ m1buf)
{
    __shared__ float sW[1024];
    for (int i = threadIdx.x; i < 1024; i += 256) sW[i] = Wm01[l * 1024 + i];
    __syncthreads();
    const int e = blockIdx.x * 8 + (threadIdx.x >> 5);
    if (e >= E) return;
    const int c = threadIdx.x & 31;
    const int lane = threadIdx.x & 63;
    const int base = lane & 32;
    const int s = src[e];
    const int slot = rev[e];
    float r0 = rhat[e * 3 + 0], r1 = rhat[e * 3 + 1], r2 = rhat[e * 3 + 2];
    const float* hp = h1 + (size_t)s * 96 + c * 3;
    float dot = hp[0] * r0 + hp[1] * r1 + hp[2] * r2;
    float t1 = 0.f;
    for (int i = 0; i < 32; ++i) {
        float di = __shfl(dot, base + i);
        t1 = fmaf(di, sW[i * 32 + c], t1);
    }
    const float* rp = rad3 + ((size_t)l * E + e) * 128;
    float w00 = rp[c], w01 = rp[32 + c], w10 = rp[64 + c], w11 = rp[96 + c];
    m0buf[(size_t)slot * 32 + c] = fmaf(w00, P00[s * 32 + c], w01 * t1);
    float u10 = w10 * P10[s * 32 + c];
    const float* pp = P11 + (size_t)s * 96 + c * 3;
    float* mp = m1buf + (size_t)slot * 96 + c * 3;
    mp[0] = fmaf(w11, pp[0], u10 * r0);
    mp[1] = fmaf(w11, pp[1], u10 * r1);
    mp[2] = fmaf(w11, pp[2], u10 * r2);
}

// ---------------- node update (attention + norms + next-layer pre / output) ----------------
__global__ __launch_bounds__(64) void k_node(
    int l, int lnext, int last, const int* __restrict__ rowptr,
    const float* __restrict__ m0buf, const float* __restrict__ m1buf,
    const float* __restrict__ qbuf,
    float* __restrict__ h0, float* __restrict__ h1,
    const float* __restrict__ Ws0, const float* __restrict__ Ws1,
    const float* __restrict__ gam0, const float* __restrict__ bet0,
    const float* __restrict__ gam1,
    const float* __restrict__ Wq, const float* __restrict__ Wm00,
    const float* __restrict__ Wm10, const float* __restrict__ Wm11,
    float* __restrict__ qout, float* __restrict__ P00,
    float* __restrict__ P10, float* __restrict__ P11,
    const float* __restrict__ x, const float* __restrict__ Wout,
    float* __restrict__ out)
{
    const int n = blockIdx.x, lane = threadIdx.x;
    const int c = lane & 31, half = lane >> 5;
    __shared__ float s_h0[32], s_a0[32], s_a1[96];
    if (lane < 32) s_h0[lane] = h0[n * CC + lane];
    __syncthreads();

    float qc = qbuf[n * 32 + c];

    float m_run = -INFINITY, l_run = 0.f;
    float a0 = 0.f, a1x = 0.f, a1y = 0.f, a1z = 0.f;
    const int st = rowptr[n], en = rowptr[n + 1];
    for (int i = st; i < en; i += 2) {
        const int idx = i + half;
        const bool valid = idx < en;
        float kc = 0.f, mv0 = 0.f, mv1 = 0.f, mv2 = 0.f;
        if (valid) {
            kc = m0buf[(size_t)idx * 32 + c];
            const float* mp = m1buf + (size_t)idx * 96 + c * 3;
            mv0 = mp[0]; mv1 = mp[1]; mv2 = mp[2];
        }
        float p = qc * kc;
        p += __shfl_xor(p, 1); p += __shfl_xor(p, 2); p += __shfl_xor(p, 4);
        if (valid) {
            float logit = p * 0.35355339059327373f;   // 1/sqrt(8)
            float mn = fmaxf(m_run, logit);
            float sc = __expf(m_run - mn);
            float w  = __expf(logit - mn);
            l_run = fmaf(l_run, sc, w);
            a0  = fmaf(a0,  sc, w * kc);
            a1x = fmaf(a1x, sc, w * mv0);
            a1y = fmaf(a1y, sc, w * mv1);
            a1z = fmaf(a1z, sc, w * mv2);
            m_run = mn;
        }
    }
    float m_o  = __shfl_xor(m_run, 32), l_o = __shfl_xor(l_run, 32);
    float a0o  = __shfl_xor(a0, 32);
    float a1xo = __shfl_xor(a1x, 32), a1yo = __shfl_xor(a1y, 32), a1zo = __shfl_xor(a1z, 32);
    float mn = fmaxf(m_run, m_o);
    float sa = 0.f, sb = 0.f;
    if (mn > -INFINITY) { sa = __expf(m_run - mn); sb = __expf(m_o - mn); }
    float den = l_run * sa + l_o * sb;
    float inv = 1.0f / (den + 1e-9f);
    float g0c = (a0  * sa + a0o  * sb) * inv;
    float g1x = (a1x * sa + a1xo * sb) * inv;
    float g1y = (a1y * sa + a1yo * sb) * inv;
    float g1z = (a1z * sa + a1zo * sb) * inv;
    if (lane < 32) {
        s_a0[c] = g0c;
        s_a1[c * 3 + 0] = g1x; s_a1[c * 3 + 1] = g1y; s_a1[c * 3 + 2] = g1z;
    }
    __syncthreads();

    // h0 self-interaction + LayerNorm
    float x0 = s_h0[c];
    {
        const float* W = Ws0 + l * 1024;
        for (int i = 0; i < 32; ++i) x0 = fmaf(s_a0[i], W[i * 32 + c], x0);
    }
    float mu = x0;
    mu += __shfl_xor(mu, 1); mu += __shfl_xor(mu, 2); mu += __shfl_xor(mu, 4);
    mu += __shfl_xor(mu, 8); mu += __shfl_xor(mu, 16);
    mu *= (1.f / 32.f);
    float sq = x0 * x0;
    sq += __shfl_xor(sq, 1); sq += __shfl_xor(sq, 2); sq += __shfl_xor(sq, 4);
    sq += __shfl_xor(sq, 8); sq += __shfl_xor(sq, 16);
    float var = sq * (1.f / 32.f) - mu * mu;
    float h0n = (x0 - mu) * rsqrtf(var + 1e-5f) * gam0[l * 32 + c] + bet0[l * 32 + c];
    if (lane < 32) h0[n * CC + c] = h0n;

    // h1 self-interaction + equivariant norm gate
    const float* hp = h1 + (size_t)n * 96 + c * 3;
    float v0 = hp[0], v1 = hp[1], v2 = hp[2];
    {
        const float* W = Ws1 + l * 1024;
        for (int i = 0; i < 32; ++i) {
            float w = W[i * 32 + c];
            v0 = fmaf(s_a1[i * 3 + 0], w, v0);
            v1 = fmaf(s_a1[i * 3 + 1], w, v1);
            v2 = fmaf(s_a1[i * 3 + 2], w, v2);
        }
    }
    float nrm = sqrtf(v0 * v0 + v1 * v1 + v2 * v2 + 1e-12f);
    float mu2 = nrm;
    mu2 += __shfl_xor(mu2, 1); mu2 += __shfl_xor(mu2, 2); mu2 += __shfl_xor(mu2, 4);
    mu2 += __shfl_xor(mu2, 8); mu2 += __shfl_xor(mu2, 16);
    mu2 *= (1.f / 32.f);
    float sq2 = nrm * nrm;
    sq2 += __shfl_xor(sq2, 1); sq2 += __shfl_xor(sq2, 2); sq2 += __shfl_xor(sq2, 4);
    sq2 += __shfl_xor(sq2, 8); sq2 += __shfl_xor(sq2, 16);
    float var2 = sq2 * (1.f / 32.f) - mu2 * mu2;
    float nln = (nrm - mu2) * rsqrtf(var2 + 1e-5f) * gam1[l * 32 + c];
    float scl = nln / (nrm + 1e-8f);
    __syncthreads();   // s_a1 reads (Ws1 loop) complete before overwrite
    if (lane < 32) {
        float* hw = h1 + (size_t)n * 96 + c * 3;
        float n0 = v0 * scl, n1 = v1 * scl, n2 = v2 * scl;
        hw[0] = n0; hw[1] = n1; hw[2] = n2;
        s_h0[c] = h0n;
        s_a1[c * 3 + 0] = n0; s_a1[c * 3 + 1] = n1; s_a1[c * 3 + 2] = n2;
    }
    __syncthreads();

    if (!last) {
        if (lane < 32) {
            const float* WqL  = Wq   + lnext * 1024;
            const float* W00L = Wm00 + lnext * 1024;
            const float* W10L = Wm10 + lnext * 1024;
            float q = 0.f, p00 = 0.f, p10 = 0.f;
            for (int i = 0; i < 32; ++i) {
                float a = s_h0[i];
                q   = fmaf(a, WqL[i * 32 + c], q);
                p00 = fmaf(a, W00L[i * 32 + c], p00);
                p10 = fmaf(a, W10L[i * 32 + c], p10);
            }
            qout[n * 32 + c] = q; P00[n * 32 + c] = p00; P10[n * 32 + c] = p10;
        } else {
            const int f = lane - 32;
            const float* W11L = Wm11 + lnext * 1024;
            float px = 0.f, py = 0.f, pz = 0.f;
            for (int i = 0; i < 32; ++i) {
                float w = W11L[i * 32 + f];
                px = fmaf(s_a1[i * 3 + 0], w, px);
                py = fmaf(s_a1[i * 3 + 1], w, py);
                pz = fmaf(s_a1[i * 3 + 2], w, pz);
            }
            float* pp = P11 + (size_t)n * 96 + f * 3;
            pp[0] = px; pp[1] = py; pp[2] = pz;
        }
    } else {
        if (lane < 3) {
            const int d = lane;
            float acc = x[n * 3 + d];
            for (int i = 0; i < 32; ++i) acc = fmaf(s_a1[i * 3 + d], Wout[i], acc);
            out[n * 3 + d] = acc;
        }
    }
}

// ---------------- launch ----------------
extern "C" void kernel_launch(void* const* d_in, const int* in_sizes, int n_in,
                              void* d_out, int out_size, void* d_ws, size_t ws_size,
                              hipStream_t stream) {
    const float* seq  = (const float*)d_in[0];
    const float* pair = (const float*)d_in[1];
    const float* bppm = (const float*)d_in[2];
    const float* x    = (const float*)d_in[3];
    const int*   src  = (const int*)d_in[4];
    const int*   dst  = (const int*)d_in[5];
    const float* Win0 = (const float*)d_in[6];
    const float* Win1 = (const float*)d_in[7];
    const float* Wr1  = (const float*)d_in[8];
    const float* br1  = (const float*)d_in[9];
    const float* Wr2  = (const float*)d_in[10];
    const float* br2  = (const float*)d_in[11];
    const float* Wm00 = (const float*)d_in[12];
    const float* Wm01 = (const float*)d_in[13];
    const float* Wm10 = (const float*)d_in[14];
    const float* Wm11 = (const float*)d_in[15];
    const float* Wq   = (const float*)d_in[16];
    const float* Ws0  = (const float*)d_in[17];
    const float* Ws1  = (const float*)d_in[18];
    const float* gam0 = (const float*)d_in[19];
    const float* bet0 = (const float*)d_in[20];
    const float* gam1 = (const float*)d_in[21];
    const float* Wout = (const float*)d_in[22];
    const int E = in_sizes[4];

    char* w = (char*)d_ws;
    auto alloc = [&](size_t nbytes) {
        void* p = (void*)w;
        w += (nbytes + 255) & ~(size_t)255;
        return p;
    };
    float* h0    = (float*)alloc((size_t)NN * CC * 4);
    float* h1    = (float*)alloc((size_t)NN * CC * 3 * 4);
    float* r_e   = (float*)alloc((size_t)E * 4);
    float* rhat  = (float*)alloc((size_t)E * 3 * 4);
    float* m0buf = (float*)alloc((size_t)E * CC * 4);
    float* m1buf = (float*)alloc((size_t)E * CC * 3 * 4);
    int* rowptr  = (int*)alloc((size_t)(NN + 1) * 4);
    int* rev     = (int*)alloc((size_t)E * 4);
    short* efh   = (short*)alloc((size_t)E * 160 * 2);
    short* efl   = (short*)alloc((size_t)E * 160 * 2);
    short* W1h   = (short*)alloc((size_t)NLAYER * 10240 * 2);
    short* W1l   = (short*)alloc((size_t)NLAYER * 10240 * 2);
    short* W2h   = (short*)alloc((size_t)NLAYER * 8192 * 2);
    short* W2l   = (short*)alloc((size_t)NLAYER * 8192 * 2);
    float* rad3  = (float*)alloc((size_t)NLAYER * E * 128 * 4);
    float* qbuf  = (float*)alloc((size_t)NN * 32 * 4);
    float* P00   = (float*)alloc((size_t)NN * 32 * 4);
    float* P10   = (float*)alloc((size_t)NN * 32 * 4);
    float* P11   = (float*)alloc((size_t)NN * 96 * 4);

    const int TB = 256;
    k_init_h0<<<NN, 64, 0, stream>>>(seq, Win0, h0);
    k_init_h1<<<(NN * CC + TB - 1) / TB, TB, 0, stream>>>(x, Win1, h1);
    k_geom<<<(E + TB - 1) / TB, TB, 0, stream>>>(src, dst, x, r_e, rhat, E);
    k_rowptr<<<(NN + 1 + TB - 1) / TB, TB, 0, stream>>>(src, rowptr, E);
    k_rev<<<(E + TB - 1) / TB, TB, 0, stream>>>(src, dst, rowptr, rev, E);
    k_build_ef<<<(E + 3) / 4, 256, 0, stream>>>(src, dst, pair, bppm, r_e, efh, efl, E);
    {
        int tot = NLAYER * 10240 + NLAYER * 8192;
        k_pack<<<(tot + TB - 1) / TB, TB, 0, stream>>>(Wr1, Wr2, W1h, W1l, W2h, W2l);
    }
    k_nodepre<<<NN / 8, 256, 0, stream>>>(0, h0, h1, Wq, Wm00, Wm10, Wm11,
                                          qbuf, P00, P10, P11);
    k_radial3<<<(E + 63) / 64, 256, 0, stream>>>(E, efh, efl, W1h, W1l, W2h, W2l,
                                                 br1, br2, rad3);

    for (int l = 0; l < NLAYER; ++l) {
        k_edge2<<<(E + 7) / 8, 256, 0, stream>>>(l, E, src, rev, rhat, rad3, h1, Wm01,
                                                 P00, P10, P11, m0buf, m1buf);
        k_node<<<NN, 64, 0, stream>>>(l, l + 1, (l == NLAYER - 1) ? 1 : 0, rowptr,
                                      m0buf, m1buf, qbuf, h0, h1,
                                      Ws0, Ws1, gam0, bet0, gam1,
                                      Wq, Wm00, Wm10, Wm11, qbuf, P00, P10, P11,
                                      x, Wout, (float*)d_out);
    }
}